// Round 5
// baseline (295.426 us; speedup 1.0000x reference)
//
#include <hip/hip_runtime.h>
#include <hip/hip_bf16.h>
#include <stdint.h>

#define B_ 4
#define S_ 2048
#define D_ 1024
#define H_ 16

typedef __attribute__((ext_vector_type(4))) float f32x4;
typedef __attribute__((ext_vector_type(8))) short short8;
typedef __attribute__((ext_vector_type(8))) unsigned short ushort8;
typedef __attribute__((ext_vector_type(4))) unsigned short ushort4v;
typedef unsigned short u16;
typedef unsigned int u32;

__device__ __forceinline__ u16 f2bf(float f){
  return __builtin_bit_cast(u16, __hip_bfloat16(f));
}
__device__ __forceinline__ float bf2f(u16 h){
  return __builtin_bit_cast(float, ((u32)h) << 16);
}
__device__ __forceinline__ f32x4 mfma16(short8 a, short8 b, f32x4 c){
  return __builtin_amdgcn_mfma_f32_16x16x32_bf16(a, b, c, 0, 0, 0);
}
__device__ __forceinline__ void gload16(const u16* g, u16* l){
  __builtin_amdgcn_global_load_lds((const __attribute__((address_space(1))) u32*)g,
                                   (__attribute__((address_space(3))) u32*)l, 16, 0, 0);
}

// ---------------- fp32 -> bf16 convert (4 elem / thread) ----------------
__global__ __launch_bounds__(256) void cvt_kernel(const float* __restrict__ in,
                                                  u16* __restrict__ out, int n4){
  int i = blockIdx.x * 256 + threadIdx.x;
  if (i >= n4) return;
  float4 v = reinterpret_cast<const float4*>(in)[i];
  uint2 o;
  o.x = (u32)f2bf(v.x) | ((u32)f2bf(v.y) << 16);
  o.y = (u32)f2bf(v.z) | ((u32)f2bf(v.w) << 16);
  reinterpret_cast<uint2*>(out)[i] = o;
}

// merged 4-weight convert: 1024 blocks per weight
__global__ __launch_bounds__(256) void cvtw_kernel(const float* __restrict__ w0, const float* __restrict__ w1,
                                                   const float* __restrict__ w2, const float* __restrict__ w3,
                                                   u16* __restrict__ o0, u16* __restrict__ o1,
                                                   u16* __restrict__ o2, u16* __restrict__ o3){
  const int which = blockIdx.x >> 10;
  const float* in = (which==0) ? w0 : (which==1) ? w1 : (which==2) ? w2 : w3;
  u16* out = (which==0) ? o0 : (which==1) ? o1 : (which==2) ? o2 : o3;
  const int i = (blockIdx.x & 1023) * 256 + threadIdx.x;
  float4 v = reinterpret_cast<const float4*>(in)[i];
  uint2 o;
  o.x = (u32)f2bf(v.x) | ((u32)f2bf(v.y) << 16);
  o.y = (u32)f2bf(v.z) | ((u32)f2bf(v.w) << 16);
  reinterpret_cast<uint2*>(out)[i] = o;
}

// ---------------- GEMM: C[M,N] = A[M,K] * B[N,K]^T (bf16 in, MODE out) ----
// m97 structure: global_load_lds width=16 into LINEAR LDS (no pad).
template<int MODE>
__global__ __launch_bounds__(256) void gemm_bt(const u16* __restrict__ A,
                                               const u16* __restrict__ Bw,
                                               void* __restrict__ C,
                                               int M, int N, int K){
  __shared__ __align__(16) u16 As[128*32];
  __shared__ __align__(16) u16 Bs[128*32];
  const int tid = threadIdx.x;
  const int lane = tid & 63, wid = tid >> 6;
  const int l16 = lane & 15, lq = lane >> 4;
  const int m0 = blockIdx.y * 128, n0 = blockIdx.x * 128;
  const int wr = (wid >> 1) * 64, wc = (wid & 1) * 64;
  const int srow = wid*32 + (lane >> 2);
  const int scol = (lane & 3) * 8;
  const u16* Ag = A  + (size_t)(m0 + srow) * K + scol;
  const u16* Bg = Bw + (size_t)(n0 + srow) * K + scol;
  u16* AsW = As + wid*32*32;
  u16* BsW = Bs + wid*32*32;
  f32x4 acc[4][4] = {};
  for (int k0 = 0; k0 < K; k0 += 32){
    __syncthreads();
    gload16(Ag + k0,            AsW);
    gload16(Ag + 16*(size_t)K + k0, AsW + 16*32);
    gload16(Bg + k0,            BsW);
    gload16(Bg + 16*(size_t)K + k0, BsW + 16*32);
    __syncthreads();
    short8 af[4], bfr[4];
#pragma unroll
    for (int i=0;i<4;i++) af[i]  = *reinterpret_cast<const short8*>(As + (wr + i*16 + l16)*32 + lq*8);
#pragma unroll
    for (int i=0;i<4;i++) bfr[i] = *reinterpret_cast<const short8*>(Bs + (wc + i*16 + l16)*32 + lq*8);
    __builtin_amdgcn_s_setprio(1);
#pragma unroll
    for (int i=0;i<4;i++)
#pragma unroll
      for (int j=0;j<4;j++) acc[i][j] = mfma16(af[i], bfr[j], acc[i][j]);
    __builtin_amdgcn_s_setprio(0);
  }
#pragma unroll
  for (int i=0;i<4;i++){
#pragma unroll
    for (int j=0;j<4;j++){
#pragma unroll
      for (int r=0;r<4;r++){
        const int m = m0 + wr + i*16 + lq*4 + r;
        const int n = n0 + wc + j*16 + l16;
        const float v = acc[i][j][r];
        if (MODE == 2){
          reinterpret_cast<float*>(C)[(size_t)m * N + n] = v;
        } else if (MODE == 0){
          reinterpret_cast<u16*>(C)[(size_t)m * N + n] = f2bf(v);
        } else {
          const int b = m >> 11, s = m & 2047;    // S_=2048
          const int h = n >> 6,  hd = n & 63;     // HD=64
          reinterpret_cast<u16*>(C)[(((size_t)(b*H_ + h) * S_ + s) << 6) + hd] = f2bf(v);
        }
      }
    }
  }
}

// ---------------- RoPE in place on Q,K stored [B*H][S][64] ----------------
// Q additionally scaled by 0.125*log2(e) (folded softmax scale, exp2 domain).
__global__ __launch_bounds__(256) void rope_kernel(u16* __restrict__ Q, u16* __restrict__ Kk){
  const int idx = blockIdx.x * 256 + threadIdx.x;   // (bh:6)(s:11)(i:5)
  const int i  = idx & 31;
  const int s  = (idx >> 5) & 2047;
  const int bh = idx >> 16;
  const float ang = (float)s * __builtin_exp2f((float)i * -0.41524101186092032f); // theta^(-i/32)
  float sn, cs;
  __sincosf(ang, &sn, &cs);
  const float QS = 0.18033688011112043f;  // 0.125 * log2(e)
  const size_t base = ((size_t)bh * S_ + s) * 64 + 2*i;
  {
    unsigned q = *reinterpret_cast<unsigned*>(Q + base);
    float x1 = bf2f((u16)q), x2 = bf2f((u16)(q >> 16));
    *reinterpret_cast<unsigned*>(Q + base) =
      (u32)f2bf((x1*cs - x2*sn)*QS) | ((u32)f2bf((x1*sn + x2*cs)*QS) << 16);
  }
  {
    unsigned k = *reinterpret_cast<unsigned*>(Kk + base);
    float x1 = bf2f((u16)k), x2 = bf2f((u16)(k >> 16));
    *reinterpret_cast<unsigned*>(Kk + base) =
      (u32)f2bf(x1*cs - x2*sn) | ((u32)f2bf(x1*sn + x2*cs) << 16);
  }
}

// ---------------- V [B,S,D] -> V^T [B*H][HD=64][S] ----------------
__global__ __launch_bounds__(256) void vt_kernel(const u16* __restrict__ V, u16* __restrict__ Vt){
  __shared__ __align__(16) u16 t[64*80];
  const int bh = blockIdx.y, b = bh >> 4, h = bh & 15;
  const int s0 = blockIdx.x * 64;
  const int tid = threadIdx.x;
  const int r = tid >> 3, seg = tid & 7;
#pragma unroll
  for (int p=0;p<2;p++){
    const int row = r + p*32;   // s offset
    ushort8 v = *reinterpret_cast<const ushort8*>(V + (size_t)(b*S_ + s0 + row)*D_ + h*64 + seg*8);
    *reinterpret_cast<ushort8*>(t + row*80 + seg*8) = v;
  }
  __syncthreads();
#pragma unroll
  for (int p=0;p<2;p++){
    const int hd = r + p*32;
    ushort8 o;
#pragma unroll
    for (int j=0;j<8;j++) o[j] = t[(seg*8+j)*80 + hd];
    *reinterpret_cast<ushort8*>(Vt + ((size_t)bh*64 + hd)*S_ + s0 + seg*8) = o;
  }
}

// ---------------- causal flash attention (S^T layout) ----------------
// Q,K: [BH][S][64] (Q pre-scaled into exp2 domain), Vt: [BH][64][S], O: [B,S,D] bf16
// S^T = mfma(K,Q): each thread holds 16 k-values for ONE q (=l16) -> softmax
// nearly lane-local (scalar m/l, 2 shfl only on rescale). O accum transposed
// via mfma(V,P). Async-STAGE: next tile's K/V global->reg loads issued before
// compute, ds_write after the end-of-tile barrier (T14).
#define APAD 68
__global__ __launch_bounds__(256) void attn_kernel(const u16* __restrict__ Q,
                                                   const u16* __restrict__ Kg,
                                                   const u16* __restrict__ Vt,
                                                   u16* __restrict__ O){
  __shared__ __align__(16) u16 Ks[64*APAD];
  __shared__ __align__(16) u16 Vs[64*APAD];
  __shared__ __align__(16) u16 Ps[4][16*APAD];
  const int bh = blockIdx.y;
  const int tid = threadIdx.x, wid = tid >> 6, lane = tid & 63;
  const int l16 = lane & 15, lq = lane >> 4;
  const u16* Qb = Q  + (size_t)bh * S_ * 64;
  const u16* Kb = Kg + (size_t)bh * S_ * 64;
  const u16* Vb = Vt + (size_t)bh * 64 * S_;
  const int b = bh >> 4, h = bh & 15;
  const int sr2 = tid >> 3, sc2 = (tid & 7) * 8;  // staging: row 0..31, col seg
  u16* Pw = &Ps[wid][0];

#pragma unroll 1
  for (int half = 0; half < 2; ++half){
    const int qt = half ? blockIdx.x : (31 - blockIdx.x);
    const int q0 = qt * 64;
    short8 qf[2];
#pragma unroll
    for (int ks=0;ks<2;ks++)
      qf[ks] = *reinterpret_cast<const short8*>(Qb + (size_t)(q0 + wid*16 + l16)*64 + ks*32 + lq*8);
    float m_run = -1e30f, l_run = 0.f;
    f32x4 oacc[4];
#pragma unroll
    for (int j=0;j<4;j++) oacc[j] = (f32x4){0.f,0.f,0.f,0.f};

    // prologue: stage tile 0
    ushort8 kreg[2], vreg[2];
#pragma unroll
    for (int p=0;p<2;p++){
      kreg[p] = *reinterpret_cast<const ushort8*>(Kb + (size_t)(sr2 + p*32)*64 + sc2);
      vreg[p] = *reinterpret_cast<const ushort8*>(Vb + (size_t)(sr2 + p*32)*S_ + sc2);
    }
    __syncthreads();   // previous half done reading Ks/Vs
#pragma unroll
    for (int p=0;p<2;p++){
      *reinterpret_cast<ushort8*>(Ks + (sr2 + p*32)*APAD + sc2) = kreg[p];
      *reinterpret_cast<ushort8*>(Vs + (sr2 + p*32)*APAD + sc2) = vreg[p];
    }
    __syncthreads();

#pragma unroll 1
    for (int kt = 0; kt <= qt; ++kt){
      // async-STAGE: issue next tile's global loads now (overlap with compute)
      if (kt < qt){
        const int kn = (kt + 1) * 64;
#pragma unroll
        for (int p=0;p<2;p++){
          kreg[p] = *reinterpret_cast<const ushort8*>(Kb + (size_t)(kn + sr2 + p*32)*64 + sc2);
          vreg[p] = *reinterpret_cast<const ushort8*>(Vb + (size_t)(sr2 + p*32)*S_ + kn + sc2);
        }
      }
      // QK^T transposed: sc[ct] rows k = ct*16+lq*4+r, col q = l16
      f32x4 sc[4];
#pragma unroll
      for (int ct=0;ct<4;ct++){
        f32x4 a = (f32x4){0.f,0.f,0.f,0.f};
#pragma unroll
        for (int ks=0;ks<2;ks++){
          short8 kf = *reinterpret_cast<const short8*>(Ks + (ct*16 + l16)*APAD + ks*32 + lq*8);
          __builtin_amdgcn_s_setprio(1);
          a = mfma16(kf, qf[ks], a);
          __builtin_amdgcn_s_setprio(0);
        }
        sc[ct] = a;
      }
      if (kt == qt){   // mask only the diagonal tile: k > q -> -inf
        const int qg = wid*16 + l16;
#pragma unroll
        for (int ct=0;ct<4;ct++){
          const int kbase = ct*16 + lq*4;
#pragma unroll
          for (int r=0;r<4;r++)
            if (kbase + r > qg) sc[ct][r] = -1e30f;
        }
      }
      // defer-max: per-lane max over this thread's 16 k-values
      float lmx = fmaxf(fmaxf(fmaxf(sc[0][0],sc[0][1]),fmaxf(sc[0][2],sc[0][3])),
                  fmaxf(fmaxf(fmaxf(sc[1][0],sc[1][1]),fmaxf(sc[1][2],sc[1][3])),
                  fmaxf(fmaxf(fmaxf(sc[2][0],sc[2][1]),fmaxf(sc[2][2],sc[2][3])),
                        fmaxf(fmaxf(sc[3][0],sc[3][1]),fmaxf(sc[3][2],sc[3][3])))));
      if (__any(lmx > m_run + 8.f)){
        float mx = lmx;
        mx = fmaxf(mx, __shfl_xor(mx, 16, 64));
        mx = fmaxf(mx, __shfl_xor(mx, 32, 64));
        mx = fmaxf(mx, m_run);
        const float alpha = __builtin_exp2f(m_run - mx);
        m_run = mx;
        l_run *= alpha;
#pragma unroll
        for (int dt=0;dt<4;dt++)
#pragma unroll
          for (int r=0;r<4;r++) oacc[dt][r] *= alpha;
      }
      // P = exp2(S - m), pack 4 consecutive k per ds_write_b64
#pragma unroll
      for (int ct=0;ct<4;ct++){
        ushort4v pk;
#pragma unroll
        for (int r=0;r<4;r++){
          const float p = __builtin_exp2f(sc[ct][r] - m_run);
          l_run += p;
          pk[r] = f2bf(p);
        }
        *reinterpret_cast<ushort4v*>(Pw + l16*APAD + ct*16 + lq*4) = pk;
      }
      asm volatile("s_waitcnt lgkmcnt(0)" ::: "memory");
      // PV transposed: oacc[dt] rows d = dt*16+lq*4+r, col q = l16
#pragma unroll
      for (int ks=0;ks<2;ks++){
        short8 pf = *reinterpret_cast<const short8*>(Pw + l16*APAD + ks*32 + lq*8);
#pragma unroll
        for (int dt=0;dt<4;dt++){
          short8 vf = *reinterpret_cast<const short8*>(Vs + (dt*16 + l16)*APAD + ks*32 + lq*8);
          __builtin_amdgcn_s_setprio(1);
          oacc[dt] = mfma16(vf, pf, oacc[dt]);
          __builtin_amdgcn_s_setprio(0);
        }
      }
      __syncthreads();   // all waves done reading Ks/Vs
      if (kt < qt){
#pragma unroll
        for (int p=0;p<2;p++){
          *reinterpret_cast<ushort8*>(Ks + (sr2 + p*32)*APAD + sc2) = kreg[p];
          *reinterpret_cast<ushort8*>(Vs + (sr2 + p*32)*APAD + sc2) = vreg[p];
        }
        __syncthreads();
      }
    }
    // epilogue: reduce l across the 4 lq-lanes sharing this q
    float lt = l_run;
    lt += __shfl_xor(lt, 16, 64);
    lt += __shfl_xor(lt, 32, 64);
    const float linv = __builtin_amdgcn_rcpf(lt);
    const int qg = q0 + wid*16 + l16;
#pragma unroll
    for (int dt=0;dt<4;dt++){
      ushort4v ov;
#pragma unroll
      for (int r=0;r<4;r++) ov[r] = f2bf(oacc[dt][r] * linv);
      *reinterpret_cast<ushort4v*>(O + (size_t)(b*S_ + qg)*D_ + h*64 + dt*16 + lq*4) = ov;
    }
  }
}

extern "C" void kernel_launch(void* const* d_in, const int* in_sizes, int n_in,
                              void* d_out, int out_size, void* d_ws, size_t ws_size,
                              hipStream_t stream){
  const float* x  = (const float*)d_in[0];
  const float* Wq = (const float*)d_in[1];
  const float* Wk = (const float*)d_in[2];
  const float* Wv = (const float*)d_in[3];
  const float* Wo = (const float*)d_in[4];
  char* ws = (char*)d_ws;
  u16* xb  = (u16*)(ws);                               // 16 MiB  x bf16
  u16* Wqb = (u16*)(ws + (16u<<20));                   // 2 MiB
  u16* Wkb = (u16*)(ws + (16u<<20) + (2u<<20));
  u16* Wvb = (u16*)(ws + (16u<<20) + (4u<<20));
  u16* Wob = (u16*)(ws + (16u<<20) + (6u<<20));
  u16* Qh  = (u16*)(ws + (24u<<20));                   // 16 MiB [BH][S][64]
  u16* Kh  = (u16*)(ws + (40u<<20));                   // 16 MiB
  u16* Vb  = (u16*)(ws + (56u<<20));                   // 16 MiB [B,S,D]
  u16* Vt  = (u16*)(ws + (72u<<20));                   // 16 MiB [BH][64][S]
  u16* Ob  = Vb;                                       // alias: V dead after vt_kernel

  cvt_kernel<<<8192, 256, 0, stream>>>(x, xb, 2097152);
  cvtw_kernel<<<4096, 256, 0, stream>>>(Wq, Wk, Wv, Wo, Wqb, Wkb, Wvb, Wob);

  dim3 gg(8, 64);
  gemm_bt<1><<<gg, 256, 0, stream>>>(xb, Wqb, Qh, 8192, 1024, 1024);
  gemm_bt<1><<<gg, 256, 0, stream>>>(xb, Wkb, Kh, 8192, 1024, 1024);
  gemm_bt<0><<<gg, 256, 0, stream>>>(xb, Wvb, Vb, 8192, 1024, 1024);

  rope_kernel<<<16384, 256, 0, stream>>>(Qh, Kh);
  vt_kernel<<<dim3(32,64), 256, 0, stream>>>(Vb, Vt);
  attn_kernel<<<dim3(16,64), 256, 0, stream>>>(Qh, Kh, Vt, Ob);

  gemm_bt<2><<<gg, 256, 0, stream>>>(Ob, Wob, d_out, 8192, 1024, 1024);
}

// Round 6
// 266.111 us; speedup vs baseline: 1.1102x; 1.1102x over previous
//
#include <hip/hip_runtime.h>
#include <hip/hip_bf16.h>
#include <stdint.h>

#define B_ 4
#define S_ 2048
#define D_ 1024
#define H_ 16

typedef __attribute__((ext_vector_type(4))) float f32x4;
typedef __attribute__((ext_vector_type(8))) short short8;
typedef __attribute__((ext_vector_type(8))) unsigned short ushort8;
typedef __attribute__((ext_vector_type(4))) unsigned short ushort4v;
typedef unsigned short u16;
typedef unsigned int u32;

__device__ __forceinline__ u16 f2bf(float f){
  return __builtin_bit_cast(u16, __hip_bfloat16(f));
}
__device__ __forceinline__ float bf2f(u16 h){
  return __builtin_bit_cast(float, ((u32)h) << 16);
}
__device__ __forceinline__ f32x4 mfma16(short8 a, short8 b, f32x4 c){
  return __builtin_amdgcn_mfma_f32_16x16x32_bf16(a, b, c, 0, 0, 0);
}
__device__ __forceinline__ void gload16(const u16* g, u16* l){
  __builtin_amdgcn_global_load_lds((const __attribute__((address_space(1))) u32*)g,
                                   (__attribute__((address_space(3))) u32*)l, 16, 0, 0);
}

// ---------------- fp32 -> bf16 convert (4 elem / thread) ----------------
__global__ __launch_bounds__(256) void cvt_kernel(const float* __restrict__ in,
                                                  u16* __restrict__ out, int n4){
  int i = blockIdx.x * 256 + threadIdx.x;
  if (i >= n4) return;
  float4 v = reinterpret_cast<const float4*>(in)[i];
  uint2 o;
  o.x = (u32)f2bf(v.x) | ((u32)f2bf(v.y) << 16);
  o.y = (u32)f2bf(v.z) | ((u32)f2bf(v.w) << 16);
  reinterpret_cast<uint2*>(out)[i] = o;
}

// merged 4-weight convert: 1024 blocks per weight
__global__ __launch_bounds__(256) void cvtw_kernel(const float* __restrict__ w0, const float* __restrict__ w1,
                                                   const float* __restrict__ w2, const float* __restrict__ w3,
                                                   u16* __restrict__ o0, u16* __restrict__ o1,
                                                   u16* __restrict__ o2, u16* __restrict__ o3){
  const int which = blockIdx.x >> 10;
  const float* in = (which==0) ? w0 : (which==1) ? w1 : (which==2) ? w2 : w3;
  u16* out = (which==0) ? o0 : (which==1) ? o1 : (which==2) ? o2 : o3;
  const int i = (blockIdx.x & 1023) * 256 + threadIdx.x;
  float4 v = reinterpret_cast<const float4*>(in)[i];
  uint2 o;
  o.x = (u32)f2bf(v.x) | ((u32)f2bf(v.y) << 16);
  o.y = (u32)f2bf(v.z) | ((u32)f2bf(v.w) << 16);
  reinterpret_cast<uint2*>(out)[i] = o;
}

// ---------------- GEMM: C[M,N] = A[M,K] * B[N,K]^T (bf16 in, MODE out) ----
// m97 structure: global_load_lds width=16 into LINEAR LDS (no pad).
template<int MODE>
__global__ __launch_bounds__(256) void gemm_bt(const u16* __restrict__ A,
                                               const u16* __restrict__ Bw,
                                               void* __restrict__ C,
                                               int M, int N, int K){
  __shared__ __align__(16) u16 As[128*32];
  __shared__ __align__(16) u16 Bs[128*32];
  const int tid = threadIdx.x;
  const int lane = tid & 63, wid = tid >> 6;
  const int l16 = lane & 15, lq = lane >> 4;
  const int m0 = blockIdx.y * 128, n0 = blockIdx.x * 128;
  const int wr = (wid >> 1) * 64, wc = (wid & 1) * 64;
  const int srow = wid*32 + (lane >> 2);
  const int scol = (lane & 3) * 8;
  const u16* Ag = A  + (size_t)(m0 + srow) * K + scol;
  const u16* Bg = Bw + (size_t)(n0 + srow) * K + scol;
  u16* AsW = As + wid*32*32;
  u16* BsW = Bs + wid*32*32;
  f32x4 acc[4][4] = {};
  for (int k0 = 0; k0 < K; k0 += 32){
    __syncthreads();
    gload16(Ag + k0,            AsW);
    gload16(Ag + 16*(size_t)K + k0, AsW + 16*32);
    gload16(Bg + k0,            BsW);
    gload16(Bg + 16*(size_t)K + k0, BsW + 16*32);
    __syncthreads();
    short8 af[4], bfr[4];
#pragma unroll
    for (int i=0;i<4;i++) af[i]  = *reinterpret_cast<const short8*>(As + (wr + i*16 + l16)*32 + lq*8);
#pragma unroll
    for (int i=0;i<4;i++) bfr[i] = *reinterpret_cast<const short8*>(Bs + (wc + i*16 + l16)*32 + lq*8);
    __builtin_amdgcn_s_setprio(1);
#pragma unroll
    for (int i=0;i<4;i++)
#pragma unroll
      for (int j=0;j<4;j++) acc[i][j] = mfma16(af[i], bfr[j], acc[i][j]);
    __builtin_amdgcn_s_setprio(0);
  }
#pragma unroll
  for (int i=0;i<4;i++){
#pragma unroll
    for (int j=0;j<4;j++){
#pragma unroll
      for (int r=0;r<4;r++){
        const int m = m0 + wr + i*16 + lq*4 + r;
        const int n = n0 + wc + j*16 + l16;
        const float v = acc[i][j][r];
        if (MODE == 2){
          reinterpret_cast<float*>(C)[(size_t)m * N + n] = v;
        } else if (MODE == 0){
          reinterpret_cast<u16*>(C)[(size_t)m * N + n] = f2bf(v);
        } else {
          const int b = m >> 11, s = m & 2047;    // S_=2048
          const int h = n >> 6,  hd = n & 63;     // HD=64
          reinterpret_cast<u16*>(C)[(((size_t)(b*H_ + h) * S_ + s) << 6) + hd] = f2bf(v);
        }
      }
    }
  }
}

// ---------------- RoPE in place on Q,K stored [B*H][S][64] ----------------
// Q additionally scaled by 0.125*log2(e) (folded softmax scale, exp2 domain).
__global__ __launch_bounds__(256) void rope_kernel(u16* __restrict__ Q, u16* __restrict__ Kk){
  const int idx = blockIdx.x * 256 + threadIdx.x;   // (bh:6)(s:11)(i:5)
  const int i  = idx & 31;
  const int s  = (idx >> 5) & 2047;
  const int bh = idx >> 16;
  const float ang = (float)s * __builtin_exp2f((float)i * -0.41524101186092032f); // theta^(-i/32)
  float sn, cs;
  __sincosf(ang, &sn, &cs);
  const float QS = 0.18033688011112043f;  // 0.125 * log2(e)
  const size_t base = ((size_t)bh * S_ + s) * 64 + 2*i;
  {
    unsigned q = *reinterpret_cast<unsigned*>(Q + base);
    float x1 = bf2f((u16)q), x2 = bf2f((u16)(q >> 16));
    *reinterpret_cast<unsigned*>(Q + base) =
      (u32)f2bf((x1*cs - x2*sn)*QS) | ((u32)f2bf((x1*sn + x2*cs)*QS) << 16);
  }
  {
    unsigned k = *reinterpret_cast<unsigned*>(Kk + base);
    float x1 = bf2f((u16)k), x2 = bf2f((u16)(k >> 16));
    *reinterpret_cast<unsigned*>(Kk + base) =
      (u32)f2bf(x1*cs - x2*sn) | ((u32)f2bf(x1*sn + x2*cs) << 16);
  }
}

// ---------------- V [B,S,D] -> V^T [B*H][HD=64][S] ----------------
__global__ __launch_bounds__(256) void vt_kernel(const u16* __restrict__ V, u16* __restrict__ Vt){
  __shared__ __align__(16) u16 t[64*80];
  const int bh = blockIdx.y, b = bh >> 4, h = bh & 15;
  const int s0 = blockIdx.x * 64;
  const int tid = threadIdx.x;
  const int r = tid >> 3, seg = tid & 7;
#pragma unroll
  for (int p=0;p<2;p++){
    const int row = r + p*32;   // s offset
    ushort8 v = *reinterpret_cast<const ushort8*>(V + (size_t)(b*S_ + s0 + row)*D_ + h*64 + seg*8);
    *reinterpret_cast<ushort8*>(t + row*80 + seg*8) = v;
  }
  __syncthreads();
#pragma unroll
  for (int p=0;p<2;p++){
    const int hd = r + p*32;
    ushort8 o;
#pragma unroll
    for (int j=0;j<8;j++) o[j] = t[(seg*8+j)*80 + hd];
    *reinterpret_cast<ushort8*>(Vt + ((size_t)bh*64 + hd)*S_ + s0 + seg*8) = o;
  }
}

// ---------------- causal flash attention (8-wave, dbuf gload_lds) ----------
// Q,K: [BH][S][64] (Q pre-scaled into exp2 domain), Vt: [BH][64][S], O: [B,S,D]
// QBLK=128 (8 waves x 16 q-rows), KVBLK=64, double-buffered K/V staged via
// global_load_lds with BOTH-SIDES XOR swizzle (linear LDS dest, pre-swizzled
// global source, swizzled ds_read) -> <=2-way bank conflicts on 128B rows.
// S^T softmax (per-lane m/l, defer-max thr=8), P via wave-private padded LDS.
// One __syncthreads per KV tile (auto-drains vmcnt for the prefetch).
#define PSPAD 68
__global__ __launch_bounds__(512) void attn_kernel(const u16* __restrict__ Q,
                                                   const u16* __restrict__ Kg,
                                                   const u16* __restrict__ Vt,
                                                   u16* __restrict__ O){
  __shared__ __align__(16) u16 KV[2][2][4096];   // [buf][K|V][row*64+col] 32 KB
  __shared__ __align__(16) u16 Ps[8][16*PSPAD];  // wave-private P, 17.4 KB
  const int bh = blockIdx.y;
  const int tid = threadIdx.x, wid = tid >> 6, lane = tid & 63;
  const int l16 = lane & 15, lq = lane >> 4;
  const int qt = 15 - ((blockIdx.x + bh) & 15);   // work-descending dispatch
  const int q0 = qt * 128;
  const u16* Qb = Q  + (size_t)bh * S_ * 64;
  const u16* Kb = Kg + (size_t)bh * S_ * 64;
  const u16* Vb = Vt + (size_t)bh * 64 * S_;
  const int b = bh >> 4, h = bh & 15;
  u16* Pw = &Ps[wid][0];

  // staging: wave wid covers rows 8w..8w+7 of the 64x64 tile (1 KB / gload)
  const int Loff = wid*512 + lane*8;                  // linear u16 offset in tile
  const int swzL = Loff ^ (((Loff >> 6) & 7) << 3);   // pre-swizzled source off
  const int vrow = Loff >> 6;                         // d-row for V
  const int vcol = swzL & 63;

  short8 qf[2];
#pragma unroll
  for (int ks=0;ks<2;ks++)
    qf[ks] = *reinterpret_cast<const short8*>(Qb + (size_t)(q0 + wid*16 + l16)*64 + ks*32 + lq*8);
  float m_run = -1e30f, l_run = 0.f;
  f32x4 oacc[4];
#pragma unroll
  for (int j=0;j<4;j++) oacc[j] = (f32x4){0.f,0.f,0.f,0.f};

  const int nt = 2*qt + 2;
  // prologue: stage tile 0 into buf 0
  gload16(Kb + swzL,                    &KV[0][0][0] + wid*512);
  gload16(Vb + (size_t)vrow*S_ + vcol,  &KV[0][1][0] + wid*512);
  __syncthreads();

#pragma unroll 1
  for (int kt = 0; kt < nt; ++kt){
    const int cur = kt & 1;
    if (kt + 1 < nt){
      const int kn = (kt + 1) * 64;
      gload16(Kb + (size_t)kn*64 + swzL,         &KV[cur^1][0][0] + wid*512);
      gload16(Vb + (size_t)vrow*S_ + kn + vcol,  &KV[cur^1][1][0] + wid*512);
    }
    const int k0 = kt * 64;
    const int rsw = (l16 & 7) << 3;   // read-side swizzle (row&7 == l16&7)
    // QK^T transposed: sc[ct] rows k = ct*16+lq*4+r, col q = l16
    f32x4 sc[4];
    __builtin_amdgcn_s_setprio(1);
#pragma unroll
    for (int ct=0;ct<4;ct++){
      f32x4 a = (f32x4){0.f,0.f,0.f,0.f};
#pragma unroll
      for (int ks=0;ks<2;ks++){
        short8 kf = *reinterpret_cast<const short8*>(
            &KV[cur][0][(ct*16 + l16)*64 + ((ks*32 + lq*8) ^ rsw)]);
        a = mfma16(kf, qf[ks], a);
      }
      sc[ct] = a;
    }
    __builtin_amdgcn_s_setprio(0);
    if (k0 + 63 > q0 + wid*16){   // mask: k > q -> -inf (diagonal region only)
      const int qg = q0 + wid*16 + l16;
#pragma unroll
      for (int ct=0;ct<4;ct++){
        const int kbase = k0 + ct*16 + lq*4;
#pragma unroll
        for (int r=0;r<4;r++)
          if (kbase + r > qg) sc[ct][r] = -1e30f;
      }
    }
    // defer-max over this thread's 16 k-values
    float lmx = fmaxf(fmaxf(fmaxf(sc[0][0],sc[0][1]),fmaxf(sc[0][2],sc[0][3])),
                fmaxf(fmaxf(fmaxf(sc[1][0],sc[1][1]),fmaxf(sc[1][2],sc[1][3])),
                fmaxf(fmaxf(fmaxf(sc[2][0],sc[2][1]),fmaxf(sc[2][2],sc[2][3])),
                      fmaxf(fmaxf(sc[3][0],sc[3][1]),fmaxf(sc[3][2],sc[3][3])))));
    if (__any(lmx > m_run + 8.f)){
      float mx = lmx;
      mx = fmaxf(mx, __shfl_xor(mx, 16, 64));
      mx = fmaxf(mx, __shfl_xor(mx, 32, 64));
      mx = fmaxf(mx, m_run);
      const float alpha = __builtin_exp2f(m_run - mx);
      m_run = mx;
      l_run *= alpha;
#pragma unroll
      for (int dt=0;dt<4;dt++)
#pragma unroll
        for (int r=0;r<4;r++) oacc[dt][r] *= alpha;
    }
    // P = exp2(S - m), 4 consecutive k per ds_write_b64
#pragma unroll
    for (int ct=0;ct<4;ct++){
      ushort4v pk;
#pragma unroll
      for (int r=0;r<4;r++){
        const float p = __builtin_exp2f(sc[ct][r] - m_run);
        l_run += p;
        pk[r] = f2bf(p);
      }
      *reinterpret_cast<ushort4v*>(Pw + l16*PSPAD + ct*16 + lq*4) = pk;
    }
    asm volatile("s_waitcnt lgkmcnt(0)" ::: "memory");
    // PV transposed: oacc[dt] rows d = dt*16+lq*4+r, col q = l16
    __builtin_amdgcn_s_setprio(1);
#pragma unroll
    for (int ks=0;ks<2;ks++){
      short8 pf = *reinterpret_cast<const short8*>(Pw + l16*PSPAD + ks*32 + lq*8);
#pragma unroll
      for (int dt=0;dt<4;dt++){
        short8 vf = *reinterpret_cast<const short8*>(
            &KV[cur][1][(dt*16 + l16)*64 + ((ks*32 + lq*8) ^ rsw)]);
        oacc[dt] = mfma16(vf, pf, oacc[dt]);
      }
    }
    __builtin_amdgcn_s_setprio(0);
    __syncthreads();   // drains vmcnt (prefetch landed) + all waves done with cur
  }
  // epilogue: reduce l across the 4 lq-lanes sharing this q
  float lt = l_run;
  lt += __shfl_xor(lt, 16, 64);
  lt += __shfl_xor(lt, 32, 64);
  const float linv = __builtin_amdgcn_rcpf(lt);
  const int qg = q0 + wid*16 + l16;
#pragma unroll
  for (int dt=0;dt<4;dt++){
    ushort4v ov;
#pragma unroll
    for (int r=0;r<4;r++) ov[r] = f2bf(oacc[dt][r] * linv);
    *reinterpret_cast<ushort4v*>(O + (size_t)(b*S_ + qg)*D_ + h*64 + dt*16 + lq*4) = ov;
  }
}

extern "C" void kernel_launch(void* const* d_in, const int* in_sizes, int n_in,
                              void* d_out, int out_size, void* d_ws, size_t ws_size,
                              hipStream_t stream){
  const float* x  = (const float*)d_in[0];
  const float* Wq = (const float*)d_in[1];
  const float* Wk = (const float*)d_in[2];
  const float* Wv = (const float*)d_in[3];
  const float* Wo = (const float*)d_in[4];
  char* ws = (char*)d_ws;
  u16* xb  = (u16*)(ws);                               // 16 MiB  x bf16
  u16* Wqb = (u16*)(ws + (16u<<20));                   // 2 MiB
  u16* Wkb = (u16*)(ws + (16u<<20) + (2u<<20));
  u16* Wvb = (u16*)(ws + (16u<<20) + (4u<<20));
  u16* Wob = (u16*)(ws + (16u<<20) + (6u<<20));
  u16* Qh  = (u16*)(ws + (24u<<20));                   // 16 MiB [BH][S][64]
  u16* Kh  = (u16*)(ws + (40u<<20));                   // 16 MiB
  u16* Vb  = (u16*)(ws + (56u<<20));                   // 16 MiB [B,S,D]
  u16* Vt  = (u16*)(ws + (72u<<20));                   // 16 MiB [BH][64][S]
  u16* Ob  = Vb;                                       // alias: V dead after vt_kernel

  cvt_kernel<<<8192, 256, 0, stream>>>(x, xb, 2097152);
  cvtw_kernel<<<4096, 256, 0, stream>>>(Wq, Wk, Wv, Wo, Wqb, Wkb, Wvb, Wob);

  dim3 gg(8, 64);
  gemm_bt<1><<<gg, 256, 0, stream>>>(xb, Wqb, Qh, 8192, 1024, 1024);
  gemm_bt<1><<<gg, 256, 0, stream>>>(xb, Wkb, Kh, 8192, 1024, 1024);
  gemm_bt<0><<<gg, 256, 0, stream>>>(xb, Wvb, Vb, 8192, 1024, 1024);

  rope_kernel<<<16384, 256, 0, stream>>>(Qh, Kh);
  vt_kernel<<<dim3(32,64), 256, 0, stream>>>(Vb, Vt);
  attn_kernel<<<dim3(16,64), 512, 0, stream>>>(Qh, Kh, Vt, Ob);

  gemm_bt<2><<<gg, 256, 0, stream>>>(Ob, Wob, d_out, 8192, 1024, 1024);
}

// Round 7
// 230.571 us; speedup vs baseline: 1.2813x; 1.1541x over previous
//
#include <hip/hip_runtime.h>
#include <hip/hip_bf16.h>
#include <stdint.h>

#define B_ 4
#define S_ 2048
#define D_ 1024
#define H_ 16

typedef __attribute__((ext_vector_type(4))) float f32x4;
typedef __attribute__((ext_vector_type(8))) short short8;
typedef __attribute__((ext_vector_type(8))) unsigned short ushort8;
typedef __attribute__((ext_vector_type(4))) unsigned short ushort4v;
typedef unsigned short u16;
typedef unsigned int u32;

__device__ __forceinline__ u16 f2bf(float f){
  return __builtin_bit_cast(u16, __hip_bfloat16(f));
}
__device__ __forceinline__ float bf2f(u16 h){
  return __builtin_bit_cast(float, ((u32)h) << 16);
}
__device__ __forceinline__ f32x4 mfma16(short8 a, short8 b, f32x4 c){
  return __builtin_amdgcn_mfma_f32_16x16x32_bf16(a, b, c, 0, 0, 0);
}
__device__ __forceinline__ void gload16(const u16* g, u16* l){
  __builtin_amdgcn_global_load_lds((const __attribute__((address_space(1))) u32*)g,
                                   (__attribute__((address_space(3))) u32*)l, 16, 0, 0);
}

// ---------------- fp32 -> bf16 convert (4 elem / thread) ----------------
__global__ __launch_bounds__(256) void cvt_kernel(const float* __restrict__ in,
                                                  u16* __restrict__ out, int n4){
  int i = blockIdx.x * 256 + threadIdx.x;
  if (i >= n4) return;
  float4 v = reinterpret_cast<const float4*>(in)[i];
  uint2 o;
  o.x = (u32)f2bf(v.x) | ((u32)f2bf(v.y) << 16);
  o.y = (u32)f2bf(v.z) | ((u32)f2bf(v.w) << 16);
  reinterpret_cast<uint2*>(out)[i] = o;
}

// merged 4-weight convert: 1024 blocks per weight
__global__ __launch_bounds__(256) void cvtw_kernel(const float* __restrict__ w0, const float* __restrict__ w1,
                                                   const float* __restrict__ w2, const float* __restrict__ w3,
                                                   u16* __restrict__ o0, u16* __restrict__ o1,
                                                   u16* __restrict__ o2, u16* __restrict__ o3){
  const int which = blockIdx.x >> 10;
  const float* in = (which==0) ? w0 : (which==1) ? w1 : (which==2) ? w2 : w3;
  u16* out = (which==0) ? o0 : (which==1) ? o1 : (which==2) ? o2 : o3;
  const int i = (blockIdx.x & 1023) * 256 + threadIdx.x;
  float4 v = reinterpret_cast<const float4*>(in)[i];
  uint2 o;
  o.x = (u32)f2bf(v.x) | ((u32)f2bf(v.y) << 16);
  o.y = (u32)f2bf(v.z) | ((u32)f2bf(v.w) << 16);
  reinterpret_cast<uint2*>(out)[i] = o;
}

// ---------------- GEMM: C[M,N] = A[M,K] * B[N,K]^T (bf16 in, MODE out) ----
// m97 structure: global_load_lds width=16 into LINEAR LDS (no pad).
// Grid: x = M-tiles (fastest -> XCD gets contiguous m-stripe, B reused in L2).
template<int MODE>
__global__ __launch_bounds__(256) void gemm_bt(const u16* __restrict__ A,
                                               const u16* __restrict__ Bw,
                                               void* __restrict__ C,
                                               int M, int N, int K){
  __shared__ __align__(16) u16 As[128*32];
  __shared__ __align__(16) u16 Bs[128*32];
  const int tid = threadIdx.x;
  const int lane = tid & 63, wid = tid >> 6;
  const int l16 = lane & 15, lq = lane >> 4;
  const int m0 = blockIdx.x * 128, n0 = blockIdx.y * 128;
  const int wr = (wid >> 1) * 64, wc = (wid & 1) * 64;
  const int srow = wid*32 + (lane >> 2);
  const int scol = (lane & 3) * 8;
  const u16* Ag = A  + (size_t)(m0 + srow) * K + scol;
  const u16* Bg = Bw + (size_t)(n0 + srow) * K + scol;
  u16* AsW = As + wid*32*32;
  u16* BsW = Bs + wid*32*32;
  f32x4 acc[4][4] = {};
  for (int k0 = 0; k0 < K; k0 += 32){
    __syncthreads();
    gload16(Ag + k0,            AsW);
    gload16(Ag + 16*(size_t)K + k0, AsW + 16*32);
    gload16(Bg + k0,            BsW);
    gload16(Bg + 16*(size_t)K + k0, BsW + 16*32);
    __syncthreads();
    short8 af[4], bfr[4];
#pragma unroll
    for (int i=0;i<4;i++) af[i]  = *reinterpret_cast<const short8*>(As + (wr + i*16 + l16)*32 + lq*8);
#pragma unroll
    for (int i=0;i<4;i++) bfr[i] = *reinterpret_cast<const short8*>(Bs + (wc + i*16 + l16)*32 + lq*8);
    __builtin_amdgcn_s_setprio(1);
#pragma unroll
    for (int i=0;i<4;i++)
#pragma unroll
      for (int j=0;j<4;j++) acc[i][j] = mfma16(af[i], bfr[j], acc[i][j]);
    __builtin_amdgcn_s_setprio(0);
  }
#pragma unroll
  for (int i=0;i<4;i++){
#pragma unroll
    for (int j=0;j<4;j++){
#pragma unroll
      for (int r=0;r<4;r++){
        const int m = m0 + wr + i*16 + lq*4 + r;
        const int n = n0 + wc + j*16 + l16;
        const float v = acc[i][j][r];
        if (MODE == 2){
          reinterpret_cast<float*>(C)[(size_t)m * N + n] = v;
        } else if (MODE == 0){
          reinterpret_cast<u16*>(C)[(size_t)m * N + n] = f2bf(v);
        } else {
          const int b = m >> 11, s = m & 2047;    // S_=2048
          const int h = n >> 6,  hd = n & 63;     // HD=64
          reinterpret_cast<u16*>(C)[(((size_t)(b*H_ + h) * S_ + s) << 6) + hd] = f2bf(v);
        }
      }
    }
  }
}

// ---------------- RoPE in place on Q,K stored [B*H][S][64] ----------------
// Q additionally scaled by 0.125*log2(e) (folded softmax scale, exp2 domain).
__global__ __launch_bounds__(256) void rope_kernel(u16* __restrict__ Q, u16* __restrict__ Kk){
  const int idx = blockIdx.x * 256 + threadIdx.x;   // (bh:6)(s:11)(i:5)
  const int i  = idx & 31;
  const int s  = (idx >> 5) & 2047;
  const int bh = idx >> 16;
  const float ang = (float)s * __builtin_exp2f((float)i * -0.41524101186092032f); // theta^(-i/32)
  float sn, cs;
  __sincosf(ang, &sn, &cs);
  const float QS = 0.18033688011112043f;  // 0.125 * log2(e)
  const size_t base = ((size_t)bh * S_ + s) * 64 + 2*i;
  {
    unsigned q = *reinterpret_cast<unsigned*>(Q + base);
    float x1 = bf2f((u16)q), x2 = bf2f((u16)(q >> 16));
    *reinterpret_cast<unsigned*>(Q + base) =
      (u32)f2bf((x1*cs - x2*sn)*QS) | ((u32)f2bf((x1*sn + x2*cs)*QS) << 16);
  }
  {
    unsigned k = *reinterpret_cast<unsigned*>(Kk + base);
    float x1 = bf2f((u16)k), x2 = bf2f((u16)(k >> 16));
    *reinterpret_cast<unsigned*>(Kk + base) =
      (u32)f2bf(x1*cs - x2*sn) | ((u32)f2bf(x1*sn + x2*cs) << 16);
  }
}

// ---------------- V [B,S,D] -> V^T [B*H][HD=64][S] ----------------
__global__ __launch_bounds__(256) void vt_kernel(const u16* __restrict__ V, u16* __restrict__ Vt){
  __shared__ __align__(16) u16 t[64*80];
  const int bh = blockIdx.y, b = bh >> 4, h = bh & 15;
  const int s0 = blockIdx.x * 64;
  const int tid = threadIdx.x;
  const int r = tid >> 3, seg = tid & 7;
#pragma unroll
  for (int p=0;p<2;p++){
    const int row = r + p*32;   // s offset
    ushort8 v = *reinterpret_cast<const ushort8*>(V + (size_t)(b*S_ + s0 + row)*D_ + h*64 + seg*8);
    *reinterpret_cast<ushort8*>(t + row*80 + seg*8) = v;
  }
  __syncthreads();
#pragma unroll
  for (int p=0;p<2;p++){
    const int hd = r + p*32;
    ushort8 o;
#pragma unroll
    for (int j=0;j<8;j++) o[j] = t[(seg*8+j)*80 + hd];
    *reinterpret_cast<ushort8*>(Vt + ((size_t)bh*64 + hd)*S_ + s0 + seg*8) = o;
  }
}

// ---------------- causal flash attention (8-wave, paired q-tiles) ----------
// Q,K: [BH][S][64] (Q pre-scaled into exp2 domain), Vt: [BH][64][S], O: [B,S,D]
// Block (bh, px) processes q-tiles {15-px, px}: exactly 36 KV-tiles/block.
// Grid 64x8 -> 512 blocks = 2/CU, zero tail; id%8 = bh%8 -> per-XCD L2 holds
// only 8 heads' K/V (4 MB). Double-buffered gload_lds staging, both-sides XOR
// swizzle. S^T softmax (per-lane m, defer-max thr=8). l via ones-MFMA: the
// PV-side mfma(ones,P) reduces the full K dim -> lacc[0] = sum_k P exactly.
#define PSPAD 68
__global__ __launch_bounds__(512) void attn_kernel(const u16* __restrict__ Q,
                                                   const u16* __restrict__ Kg,
                                                   const u16* __restrict__ Vt,
                                                   u16* __restrict__ O){
  __shared__ __align__(16) u16 KV[2][2][4096];   // [buf][K|V][row*64+col] 32 KB
  __shared__ __align__(16) u16 Ps[8][16*PSPAD];  // wave-private P, 17.4 KB
  const int bh = blockIdx.x;                     // fastest -> XCD = bh%8
  const int px = blockIdx.y;                     // pair index 0..7
  const int tid = threadIdx.x, wid = tid >> 6, lane = tid & 63;
  const int l16 = lane & 15, lq = lane >> 4;
  const u16* Qb = Q  + (size_t)bh * S_ * 64;
  const u16* Kb = Kg + (size_t)bh * S_ * 64;
  const u16* Vb = Vt + (size_t)bh * 64 * S_;
  const int b = bh >> 4, h = bh & 15;
  u16* Pw = &Ps[wid][0];
  const short8 ones8 = {0x3F80,0x3F80,0x3F80,0x3F80,0x3F80,0x3F80,0x3F80,0x3F80};

  // staging: wave wid covers rows 8w..8w+7 of the 64x64 tile (1 KB / gload)
  const int Loff = wid*512 + lane*8;                  // linear u16 offset in tile
  const int swzL = Loff ^ (((Loff >> 6) & 7) << 3);   // pre-swizzled source off
  const int vrow = Loff >> 6;                         // d-row for V
  const int vcol = swzL & 63;
  const int rsw = (l16 & 7) << 3;                     // read-side swizzle

#pragma unroll 1
  for (int half = 0; half < 2; ++half){
    const int qt = half ? px : (15 - px);
    const int q0 = qt * 128;
    short8 qf[2];
#pragma unroll
    for (int ks=0;ks<2;ks++)
      qf[ks] = *reinterpret_cast<const short8*>(Qb + (size_t)(q0 + wid*16 + l16)*64 + ks*32 + lq*8);
    float m_run = -1e30f;
    f32x4 oacc[4], lacc = (f32x4){0.f,0.f,0.f,0.f};
#pragma unroll
    for (int j=0;j<4;j++) oacc[j] = (f32x4){0.f,0.f,0.f,0.f};

    const int nt = 2*qt + 2;
    // prologue: stage tile 0 into buf 0
    gload16(Kb + swzL,                    &KV[0][0][0] + wid*512);
    gload16(Vb + (size_t)vrow*S_ + vcol,  &KV[0][1][0] + wid*512);
    __syncthreads();

#pragma unroll 1
    for (int kt = 0; kt < nt; ++kt){
      const int cur = kt & 1;
      if (kt + 1 < nt){
        const int kn = (kt + 1) * 64;
        gload16(Kb + (size_t)kn*64 + swzL,         &KV[cur^1][0][0] + wid*512);
        gload16(Vb + (size_t)vrow*S_ + kn + vcol,  &KV[cur^1][1][0] + wid*512);
      }
      const int k0 = kt * 64;
      if (k0 <= q0 + wid*16 + 15){   // wave has at least one unmasked row
        // QK^T transposed: sc[ct] rows k = ct*16+lq*4+r, col q = l16
        f32x4 sc[4];
        __builtin_amdgcn_s_setprio(1);
#pragma unroll
        for (int ct=0;ct<4;ct++){
          f32x4 a = (f32x4){0.f,0.f,0.f,0.f};
#pragma unroll
          for (int ks=0;ks<2;ks++){
            short8 kf = *reinterpret_cast<const short8*>(
                &KV[cur][0][(ct*16 + l16)*64 + ((ks*32 + lq*8) ^ rsw)]);
            a = mfma16(kf, qf[ks], a);
          }
          sc[ct] = a;
        }
        __builtin_amdgcn_s_setprio(0);
        if (k0 + 63 > q0 + wid*16){   // mask: k > q -> -inf (diagonal region)
          const int qg = q0 + wid*16 + l16;
#pragma unroll
          for (int ct=0;ct<4;ct++){
            const int kbase = k0 + ct*16 + lq*4;
#pragma unroll
            for (int r=0;r<4;r++)
              if (kbase + r > qg) sc[ct][r] = -1e30f;
          }
        }
        // defer-max over this thread's 16 k-values
        float lmx = fmaxf(fmaxf(fmaxf(sc[0][0],sc[0][1]),fmaxf(sc[0][2],sc[0][3])),
                    fmaxf(fmaxf(fmaxf(sc[1][0],sc[1][1]),fmaxf(sc[1][2],sc[1][3])),
                    fmaxf(fmaxf(fmaxf(sc[2][0],sc[2][1]),fmaxf(sc[2][2],sc[2][3])),
                          fmaxf(fmaxf(sc[3][0],sc[3][1]),fmaxf(sc[3][2],sc[3][3])))));
        if (__any(lmx > m_run + 8.f)){
          float mx = lmx;
          mx = fmaxf(mx, __shfl_xor(mx, 16, 64));
          mx = fmaxf(mx, __shfl_xor(mx, 32, 64));
          mx = fmaxf(mx, m_run);
          const float alpha = __builtin_exp2f(m_run - mx);
          m_run = mx;
#pragma unroll
          for (int r=0;r<4;r++) lacc[r] *= alpha;
#pragma unroll
          for (int dt=0;dt<4;dt++)
#pragma unroll
            for (int r=0;r<4;r++) oacc[dt][r] *= alpha;
        }
        // P = exp2(S - m), 4 consecutive k per ds_write_b64
#pragma unroll
        for (int ct=0;ct<4;ct++){
          ushort4v pk;
#pragma unroll
          for (int r=0;r<4;r++)
            pk[r] = f2bf(__builtin_exp2f(sc[ct][r] - m_run));
          *reinterpret_cast<ushort4v*>(Pw + l16*PSPAD + ct*16 + lq*4) = pk;
        }
        asm volatile("s_waitcnt lgkmcnt(0)" ::: "memory");
        // PV transposed: oacc[dt] rows d = dt*16+lq*4+r, col q = l16
        __builtin_amdgcn_s_setprio(1);
#pragma unroll
        for (int ks=0;ks<2;ks++){
          short8 pf = *reinterpret_cast<const short8*>(Pw + l16*PSPAD + ks*32 + lq*8);
          lacc = mfma16(ones8, pf, lacc);   // row-sum of P (full K reduction)
#pragma unroll
          for (int dt=0;dt<4;dt++){
            short8 vf = *reinterpret_cast<const short8*>(
                &KV[cur][1][(dt*16 + l16)*64 + ((ks*32 + lq*8) ^ rsw)]);
            oacc[dt] = mfma16(vf, pf, oacc[dt]);
          }
        }
        __builtin_amdgcn_s_setprio(0);
      }
      __syncthreads();   // drains vmcnt (prefetch landed) + all waves done with cur
    }
    // epilogue: lacc[0] == sum_k P for q=l16 (already fully reduced)
    const float linv = __builtin_amdgcn_rcpf(lacc[0]);
    const int qg = q0 + wid*16 + l16;
#pragma unroll
    for (int dt=0;dt<4;dt++){
      ushort4v ov;
#pragma unroll
      for (int r=0;r<4;r++) ov[r] = f2bf(oacc[dt][r] * linv);
      *reinterpret_cast<ushort4v*>(O + (size_t)(b*S_ + qg)*D_ + h*64 + dt*16 + lq*4) = ov;
    }
  }
}

extern "C" void kernel_launch(void* const* d_in, const int* in_sizes, int n_in,
                              void* d_out, int out_size, void* d_ws, size_t ws_size,
                              hipStream_t stream){
  const float* x  = (const float*)d_in[0];
  const float* Wq = (const float*)d_in[1];
  const float* Wk = (const float*)d_in[2];
  const float* Wv = (const float*)d_in[3];
  const float* Wo = (const float*)d_in[4];
  char* ws = (char*)d_ws;
  u16* xb  = (u16*)(ws);                               // 16 MiB  x bf16
  u16* Wqb = (u16*)(ws + (16u<<20));                   // 2 MiB
  u16* Wkb = (u16*)(ws + (16u<<20) + (2u<<20));
  u16* Wvb = (u16*)(ws + (16u<<20) + (4u<<20));
  u16* Wob = (u16*)(ws + (16u<<20) + (6u<<20));
  u16* Qh  = (u16*)(ws + (24u<<20));                   // 16 MiB [BH][S][64]
  u16* Kh  = (u16*)(ws + (40u<<20));                   // 16 MiB
  u16* Vb  = (u16*)(ws + (56u<<20));                   // 16 MiB [B,S,D]
  u16* Vt  = (u16*)(ws + (72u<<20));                   // 16 MiB [BH][64][S]
  u16* Ob  = Vb;                                       // alias: V dead after vt_kernel

  cvt_kernel<<<8192, 256, 0, stream>>>(x, xb, 2097152);
  cvtw_kernel<<<4096, 256, 0, stream>>>(Wq, Wk, Wv, Wo, Wqb, Wkb, Wvb, Wob);

  dim3 gg(64, 8);
  gemm_bt<1><<<gg, 256, 0, stream>>>(xb, Wqb, Qh, 8192, 1024, 1024);
  gemm_bt<1><<<gg, 256, 0, stream>>>(xb, Wkb, Kh, 8192, 1024, 1024);
  gemm_bt<0><<<gg, 256, 0, stream>>>(xb, Wvb, Vb, 8192, 1024, 1024);

  rope_kernel<<<16384, 256, 0, stream>>>(Qh, Kh);
  vt_kernel<<<dim3(32,64), 256, 0, stream>>>(Vb, Vt);
  attn_kernel<<<dim3(64,8), 512, 0, stream>>>(Qh, Kh, Vt, Ob);

  gemm_bt<2><<<gg, 256, 0, stream>>>(Ob, Wob, d_out, 8192, 1024, 1024);
}

// Round 9
// 227.950 us; speedup vs baseline: 1.2960x; 1.0115x over previous
//
#include <hip/hip_runtime.h>
#include <hip/hip_bf16.h>
#include <stdint.h>

#define B_ 4
#define S_ 2048
#define D_ 1024
#define H_ 16

typedef __attribute__((ext_vector_type(4))) float f32x4;
typedef __attribute__((ext_vector_type(8))) short short8;
typedef __attribute__((ext_vector_type(8))) unsigned short ushort8;
typedef unsigned short u16;
typedef unsigned int u32;

__device__ __forceinline__ u16 f2bf(float f){
  return __builtin_bit_cast(u16, __hip_bfloat16(f));
}
__device__ __forceinline__ u32 pk2bf(float a, float b){
  return (u32)f2bf(a) | ((u32)f2bf(b) << 16);   // compiler fuses to v_cvt_pk_bf16_f32
}
__device__ __forceinline__ float bf2f(u16 h){
  return __builtin_bit_cast(float, ((u32)h) << 16);
}
__device__ __forceinline__ f32x4 mfma16(short8 a, short8 b, f32x4 c){
  return __builtin_amdgcn_mfma_f32_16x16x32_bf16(a, b, c, 0, 0, 0);
}
__device__ __forceinline__ void gload16(const u16* g, u16* l){
  __builtin_amdgcn_global_load_lds((const __attribute__((address_space(1))) u32*)g,
                                   (__attribute__((address_space(3))) u32*)l, 16, 0, 0);
}

// ---------------- fp32 -> bf16 convert (4 elem / thread) ----------------
__global__ __launch_bounds__(256) void cvt_kernel(const float* __restrict__ in,
                                                  u16* __restrict__ out, int n4){
  int i = blockIdx.x * 256 + threadIdx.x;
  if (i >= n4) return;
  float4 v = reinterpret_cast<const float4*>(in)[i];
  uint2 o;
  o.x = pk2bf(v.x, v.y);
  o.y = pk2bf(v.z, v.w);
  reinterpret_cast<uint2*>(out)[i] = o;
}

// merged 4-weight convert: 1024 blocks per weight
__global__ __launch_bounds__(256) void cvtw_kernel(const float* __restrict__ w0, const float* __restrict__ w1,
                                                   const float* __restrict__ w2, const float* __restrict__ w3,
                                                   u16* __restrict__ o0, u16* __restrict__ o1,
                                                   u16* __restrict__ o2, u16* __restrict__ o3){
  const int which = blockIdx.x >> 10;
  const float* in = (which==0) ? w0 : (which==1) ? w1 : (which==2) ? w2 : w3;
  u16* out = (which==0) ? o0 : (which==1) ? o1 : (which==2) ? o2 : o3;
  const int i = (blockIdx.x & 1023) * 256 + threadIdx.x;
  float4 v = reinterpret_cast<const float4*>(in)[i];
  uint2 o;
  o.x = pk2bf(v.x, v.y);
  o.y = pk2bf(v.z, v.w);
  reinterpret_cast<uint2*>(out)[i] = o;
}

// ---------------- RoPE cos/sin table: tab[s*32+i] = (cos, sin) ------------
__global__ __launch_bounds__(256) void trig_kernel(float2* __restrict__ tab){
  const int idx = blockIdx.x * 256 + threadIdx.x;   // 65536
  const int i = idx & 31, s = idx >> 5;
  const float ang = (float)s * __builtin_exp2f((float)i * -0.41524101186092032f);
  float sn, cs;
  __sincosf(ang, &sn, &cs);
  tab[idx] = make_float2(cs, sn);
}

// ---------------- GEMM: C[M,N] = A[M,K] * B[N,K]^T (bf16 in) -------------
// m97 structure: global_load_lds width=16 into LINEAR LDS (no pad).
// MODE 0: bf16 [M][N]; MODE 1: Q = rope(scale) -> [B,H,S,HD];
// MODE 2: f32 [M][N];  MODE 3: K = rope -> [B,H,S,HD].
template<int MODE>
__global__ __launch_bounds__(256) void gemm_bt(const u16* __restrict__ A,
                                               const u16* __restrict__ Bw,
                                               void* __restrict__ C,
                                               const float2* __restrict__ tab,
                                               int M, int N, int K){
  __shared__ __align__(16) u16 As[128*32];
  __shared__ __align__(16) u16 Bs[128*32];
  const int tid = threadIdx.x;
  const int lane = tid & 63, wid = tid >> 6;
  const int l16 = lane & 15, lq = lane >> 4;
  const int m0 = blockIdx.x * 128, n0 = blockIdx.y * 128;
  const int wr = (wid >> 1) * 64, wc = (wid & 1) * 64;
  const int srow = wid*32 + (lane >> 2);
  const int scol = (lane & 3) * 8;
  const u16* Ag = A  + (size_t)(m0 + srow) * K + scol;
  const u16* Bg = Bw + (size_t)(n0 + srow) * K + scol;
  u16* AsW = As + wid*32*32;
  u16* BsW = Bs + wid*32*32;
  f32x4 acc[4][4] = {};
  for (int k0 = 0; k0 < K; k0 += 32){
    __syncthreads();
    gload16(Ag + k0,            AsW);
    gload16(Ag + 16*(size_t)K + k0, AsW + 16*32);
    gload16(Bg + k0,            BsW);
    gload16(Bg + 16*(size_t)K + k0, BsW + 16*32);
    __syncthreads();
    short8 af[4], bfr[4];
#pragma unroll
    for (int i=0;i<4;i++) af[i]  = *reinterpret_cast<const short8*>(As + (wr + i*16 + l16)*32 + lq*8);
#pragma unroll
    for (int i=0;i<4;i++) bfr[i] = *reinterpret_cast<const short8*>(Bs + (wc + i*16 + l16)*32 + lq*8);
    __builtin_amdgcn_s_setprio(1);
#pragma unroll
    for (int i=0;i<4;i++)
#pragma unroll
      for (int j=0;j<4;j++) acc[i][j] = mfma16(af[i], bfr[j], acc[i][j]);
    __builtin_amdgcn_s_setprio(0);
  }
  const float QS = 0.18033688011112043f;  // 0.125 * log2(e)
#pragma unroll
  for (int i=0;i<4;i++){
#pragma unroll
    for (int j=0;j<4;j++){
#pragma unroll
      for (int r=0;r<4;r++){
        const int m = m0 + wr + i*16 + lq*4 + r;
        const int n = n0 + wc + j*16 + l16;
        float v = acc[i][j][r];
        if (MODE == 2){
          reinterpret_cast<float*>(C)[(size_t)m * N + n] = v;
        } else if (MODE == 0){
          reinterpret_cast<u16*>(C)[(size_t)m * N + n] = f2bf(v);
        } else {
          const int b = m >> 11, s = m & 2047;    // S_=2048
          const int h = n >> 6,  hd = n & 63;     // HD=64
          // RoPE: even lane holds x1, odd holds x2 of the (2i,2i+1) pair.
          const float2 t = tab[(s << 5) + (hd >> 1)];
          const float partner = __shfl_xor(v, 1, 64);
          const float pm = (hd & 1) ? partner : -partner;
          float o = fmaf(v, t.x, pm * t.y);
          if (MODE == 1) o *= QS;
          reinterpret_cast<u16*>(C)[(((size_t)(b*H_ + h) * S_ + s) << 6) + hd] = f2bf(o);
        }
      }
    }
  }
}

// ---------------- V [B,S,D] -> V^T [B*H][HD=64][S] ----------------
__global__ __launch_bounds__(256) void vt_kernel(const u16* __restrict__ V, u16* __restrict__ Vt){
  __shared__ __align__(16) u16 t[64*80];
  const int bh = blockIdx.y, b = bh >> 4, h = bh & 15;
  const int s0 = blockIdx.x * 64;
  const int tid = threadIdx.x;
  const int r = tid >> 3, seg = tid & 7;
#pragma unroll
  for (int p=0;p<2;p++){
    const int row = r + p*32;   // s offset
    ushort8 v = *reinterpret_cast<const ushort8*>(V + (size_t)(b*S_ + s0 + row)*D_ + h*64 + seg*8);
    *reinterpret_cast<ushort8*>(t + row*80 + seg*8) = v;
  }
  __syncthreads();
#pragma unroll
  for (int p=0;p<2;p++){
    const int hd = r + p*32;
    ushort8 o;
#pragma unroll
    for (int j=0;j<8;j++) o[j] = t[(seg*8+j)*80 + hd];
    *reinterpret_cast<ushort8*>(Vt + ((size_t)bh*64 + hd)*S_ + s0 + seg*8) = o;
  }
}

// ---------------- causal flash attention (8-wave, paired q-tiles) ----------
// Q,K: [BH][S][64] (Q pre-scaled into exp2 domain), Vt: [BH][64][S], O: [B,S,D]
// Block (bh, px): q-tiles {15-px, px} -> exactly 34 KV-tiles; grid 64x8 =
// 2 blocks/CU, zero tail; bh fastest -> per-XCD L2 holds 8 heads' K/V.
// dbuf gload_lds staging, both-sides XOR swizzle, S^T softmax (per-lane m,
// defer-max thr=8), l via ones-MFMA, per-ct wave-uniform diagonal skip.
#define PSPAD 68
__global__ __launch_bounds__(512) void attn_kernel(const u16* __restrict__ Q,
                                                   const u16* __restrict__ Kg,
                                                   const u16* __restrict__ Vt,
                                                   u16* __restrict__ O){
  __shared__ __align__(16) u16 KV[2][2][4096];   // [buf][K|V][row*64+col] 32 KB
  __shared__ __align__(16) u16 Ps[8][16*PSPAD];  // wave-private P, 17.4 KB
  const int bh = blockIdx.x;                     // fastest -> XCD = bh%8
  const int px = blockIdx.y;                     // pair index 0..7
  const int tid = threadIdx.x, wid = tid >> 6, lane = tid & 63;
  const int l16 = lane & 15, lq = lane >> 4;
  const u16* Qb = Q  + (size_t)bh * S_ * 64;
  const u16* Kb = Kg + (size_t)bh * S_ * 64;
  const u16* Vb = Vt + (size_t)bh * 64 * S_;
  const int b = bh >> 4, h = bh & 15;
  u16* Pw = &Ps[wid][0];
  const short8 ones8 = {0x3F80,0x3F80,0x3F80,0x3F80,0x3F80,0x3F80,0x3F80,0x3F80};

  // staging: wave wid covers rows 8w..8w+7 of the 64x64 tile (1 KB / gload)
  const int Loff = wid*512 + lane*8;                  // linear u16 offset in tile
  const int swzL = Loff ^ (((Loff >> 6) & 7) << 3);   // pre-swizzled source off
  const int vrow = Loff >> 6;                         // d-row for V
  const int vcol = swzL & 63;
  const int rsw = (l16 & 7) << 3;                     // read-side swizzle
  // hoisted LDS read addresses (u16 index); per-ct/dt offsets are immediates
  const int kadr0 = l16*64 + ((lq*8) ^ rsw);
  const int kadr1 = l16*64 + ((32 + lq*8) ^ rsw);
  const int pwadr = l16*PSPAD + lq*4;
  const int pradr = l16*PSPAD + lq*8;

#pragma unroll 1
  for (int half = 0; half < 2; ++half){
    const int qt = half ? px : (15 - px);
    const int q0 = qt * 128;
    const int qmax_w = q0 + wid*16 + 15;  // max q row of this wave
    short8 qf[2];
#pragma unroll
    for (int ks=0;ks<2;ks++)
      qf[ks] = *reinterpret_cast<const short8*>(Qb + (size_t)(q0 + wid*16 + l16)*64 + ks*32 + lq*8);
    float m_run = -1e30f;
    f32x4 oacc[4], lacc = (f32x4){0.f,0.f,0.f,0.f};
#pragma unroll
    for (int j=0;j<4;j++) oacc[j] = (f32x4){0.f,0.f,0.f,0.f};

    const int nt = 2*qt + 2;
    // prologue: stage tile 0 into buf 0
    gload16(Kb + swzL,                    &KV[0][0][0] + wid*512);
    gload16(Vb + (size_t)vrow*S_ + vcol,  &KV[0][1][0] + wid*512);
    __syncthreads();

#pragma unroll 1
    for (int kt = 0; kt < nt; ++kt){
      const int cur = kt & 1;
      if (kt + 1 < nt){
        const int kn = (kt + 1) * 64;
        gload16(Kb + (size_t)kn*64 + swzL,         &KV[cur^1][0][0] + wid*512);
        gload16(Vb + (size_t)vrow*S_ + kn + vcol,  &KV[cur^1][1][0] + wid*512);
      }
      const int k0 = kt * 64;
      if (k0 <= qmax_w){   // wave has at least one unmasked row
        const u16* Kc = &KV[cur][0][0];
        const u16* Vc = &KV[cur][1][0];
        // QK^T transposed: sc[ct] rows k = k0+ct*16+lq*4+r, col q = l16
        f32x4 sc[4];
        __builtin_amdgcn_s_setprio(1);
#pragma unroll
        for (int ct=0;ct<4;ct++){
          if (k0 + ct*16 <= qmax_w){   // wave-uniform diagonal ct-skip
            short8 kf0 = *reinterpret_cast<const short8*>(Kc + kadr0 + ct*1024);
            short8 kf1 = *reinterpret_cast<const short8*>(Kc + kadr1 + ct*1024);
            f32x4 a = mfma16(kf0, qf[0], (f32x4){0.f,0.f,0.f,0.f});
            sc[ct] = mfma16(kf1, qf[1], a);
          } else {
            sc[ct] = (f32x4){-1e30f,-1e30f,-1e30f,-1e30f};
          }
        }
        __builtin_amdgcn_s_setprio(0);
        if (k0 + 63 > q0 + wid*16){   // element mask in diagonal tiles
          const int qg = q0 + wid*16 + l16;
#pragma unroll
          for (int ct=0;ct<4;ct++){
            const int kbase = k0 + ct*16 + lq*4;
#pragma unroll
            for (int r=0;r<4;r++)
              if (kbase + r > qg) sc[ct][r] = -1e30f;
          }
        }
        // defer-max: max3-friendly triplet tree over 16 values
        float a0 = fmaxf(fmaxf(sc[0][0], sc[0][1]), sc[0][2]);
        float a1 = fmaxf(fmaxf(sc[0][3], sc[1][0]), sc[1][1]);
        float a2 = fmaxf(fmaxf(sc[1][2], sc[1][3]), sc[2][0]);
        float a3 = fmaxf(fmaxf(sc[2][1], sc[2][2]), sc[2][3]);
        float a4 = fmaxf(fmaxf(sc[3][0], sc[3][1]), sc[3][2]);
        float b0 = fmaxf(fmaxf(a0, a1), a2);
        float b1 = fmaxf(fmaxf(a3, a4), sc[3][3]);
        float lmx = fmaxf(b0, b1);
        if (__any(lmx > m_run + 8.f)){
          float mx = lmx;
          mx = fmaxf(mx, __shfl_xor(mx, 16, 64));
          mx = fmaxf(mx, __shfl_xor(mx, 32, 64));
          mx = fmaxf(mx, m_run);
          const float alpha = __builtin_exp2f(m_run - mx);
          m_run = mx;
#pragma unroll
          for (int r=0;r<4;r++) lacc[r] *= alpha;
#pragma unroll
          for (int dt=0;dt<4;dt++)
#pragma unroll
            for (int r=0;r<4;r++) oacc[dt][r] *= alpha;
        }
        // P = exp2(S - m), packed cvt, 1 ds_write_b64 per ct (zeros if skipped)
#pragma unroll
        for (int ct=0;ct<4;ct++){
          uint2 w;
          if (k0 + ct*16 <= qmax_w){
            const float p0 = __builtin_exp2f(sc[ct][0] - m_run);
            const float p1 = __builtin_exp2f(sc[ct][1] - m_run);
            const float p2 = __builtin_exp2f(sc[ct][2] - m_run);
            const float p3 = __builtin_exp2f(sc[ct][3] - m_run);
            w.x = pk2bf(p0, p1);
            w.y = pk2bf(p2, p3);
          } else {
            w.x = 0u; w.y = 0u;
          }
          *reinterpret_cast<uint2*>(Pw + pwadr + ct*16) = w;
        }
        asm volatile("s_waitcnt lgkmcnt(0)" ::: "memory");
        // PV transposed: oacc[dt] rows d = dt*16+lq*4+r, col q = l16
        __builtin_amdgcn_s_setprio(1);
#pragma unroll
        for (int ks=0;ks<2;ks++){
          short8 pf = *reinterpret_cast<const short8*>(Pw + pradr + ks*32);
          lacc = mfma16(ones8, pf, lacc);   // row-sum of P (full K reduction)
          const int va = ks ? kadr1 : kadr0;
#pragma unroll
          for (int dt=0;dt<4;dt++){
            short8 vf = *reinterpret_cast<const short8*>(Vc + va + dt*1024);
            oacc[dt] = mfma16(vf, pf, oacc[dt]);
          }
        }
        __builtin_amdgcn_s_setprio(0);
      }
      __syncthreads();   // drains vmcnt (prefetch landed) + all waves done with cur
    }
    // epilogue: lacc[0] == sum_k P for q=l16 (already fully reduced)
    const float linv = __builtin_amdgcn_rcpf(lacc[0]);
    const int qg = q0 + wid*16 + l16;
#pragma unroll
    for (int dt=0;dt<4;dt++){
      uint2 ov;
      ov.x = pk2bf(oacc[dt][0] * linv, oacc[dt][1] * linv);
      ov.y = pk2bf(oacc[dt][2] * linv, oacc[dt][3] * linv);
      *reinterpret_cast<uint2*>(O + (size_t)(b*S_ + qg)*D_ + h*64 + dt*16 + lq*4) = ov;
    }
  }
}

extern "C" void kernel_launch(void* const* d_in, const int* in_sizes, int n_in,
                              void* d_out, int out_size, void* d_ws, size_t ws_size,
                              hipStream_t stream){
  const float* x  = (const float*)d_in[0];
  const float* Wq = (const float*)d_in[1];
  const float* Wk = (const float*)d_in[2];
  const float* Wv = (const float*)d_in[3];
  const float* Wo = (const float*)d_in[4];
  char* ws = (char*)d_ws;
  u16* xb  = (u16*)(ws);                               // 16 MiB  x bf16
  u16* Wqb = (u16*)(ws + (16u<<20));                   // 2 MiB
  u16* Wkb = (u16*)(ws + (16u<<20) + (2u<<20));
  u16* Wvb = (u16*)(ws + (16u<<20) + (4u<<20));
  u16* Wob = (u16*)(ws + (16u<<20) + (6u<<20));
  u16* Qh  = (u16*)(ws + (24u<<20));                   // 16 MiB [BH][S][64]
  u16* Kh  = (u16*)(ws + (40u<<20));                   // 16 MiB
  u16* Vb  = (u16*)(ws + (56u<<20));                   // 16 MiB [B,S,D]
  u16* Vt  = (u16*)(ws + (72u<<20));                   // 16 MiB [BH][64][S]
  float2* tab = (float2*)(ws + (88u<<20));             // 512 KiB rope table
  u16* Ob  = Vb;                                       // alias: V dead after vt_kernel

  cvt_kernel<<<8192, 256, 0, stream>>>(x, xb, 2097152);
  cvtw_kernel<<<4096, 256, 0, stream>>>(Wq, Wk, Wv, Wo, Wqb, Wkb, Wvb, Wob);
  trig_kernel<<<256, 256, 0, stream>>>(tab);

  dim3 gg(64, 8);
  gemm_bt<1><<<gg, 256, 0, stream>>>(xb, Wqb, Qh, tab, 8192, 1024, 1024);
  gemm_bt<3><<<gg, 256, 0, stream>>>(xb, Wkb, Kh, tab, 8192, 1024, 1024);
  gemm_bt<0><<<gg, 256, 0, stream>>>(xb, Wvb, Vb, nullptr, 8192, 1024, 1024);

  vt_kernel<<<dim3(32,64), 256, 0, stream>>>(Vb, Vt);
  attn_kernel<<<dim3(64,8), 512, 0, stream>>>(Qh, Kh, Vt, Ob);

  gemm_bt<2><<<gg, 256, 0, stream>>>(Ob, Wob, d_out, nullptr, 8192, 1024, 1024);
}

// Round 10
// 215.143 us; speedup vs baseline: 1.3732x; 1.0595x over previous
//
#include <hip/hip_runtime.h>
#include <hip/hip_bf16.h>
#include <stdint.h>

#define B_ 4
#define S_ 2048
#define D_ 1024
#define H_ 16

typedef __attribute__((ext_vector_type(4))) float f32x4;
typedef __attribute__((ext_vector_type(16))) float f32x16;
typedef __attribute__((ext_vector_type(8))) short short8;
typedef __attribute__((ext_vector_type(8))) unsigned short ushort8;
typedef __attribute__((ext_vector_type(4))) unsigned int u32x4;
typedef unsigned short u16;
typedef unsigned int u32;

__device__ __forceinline__ u16 f2bf(float f){
  return __builtin_bit_cast(u16, __hip_bfloat16(f));
}
__device__ __forceinline__ u32 pk2bf(float a, float b){
  return (u32)f2bf(a) | ((u32)f2bf(b) << 16);   // fuses to v_cvt_pk_bf16_f32
}
__device__ __forceinline__ f32x4 mfma16(short8 a, short8 b, f32x4 c){
  return __builtin_amdgcn_mfma_f32_16x16x32_bf16(a, b, c, 0, 0, 0);
}
__device__ __forceinline__ f32x16 mfma32(short8 a, short8 b, f32x16 c){
  return __builtin_amdgcn_mfma_f32_32x32x16_bf16(a, b, c, 0, 0, 0);
}
// x,y: swap upper half of x with lower half of y (v_permlane32_swap_b32)
__device__ __forceinline__ void plswap(u32 &x, u32 &y){
  asm volatile("v_permlane32_swap_b32 %0, %1" : "+v"(x), "+v"(y));
}
__device__ __forceinline__ void gload16(const u16* g, u16* l){
  __builtin_amdgcn_global_load_lds((const __attribute__((address_space(1))) u32*)g,
                                   (__attribute__((address_space(3))) u32*)l, 16, 0, 0);
}

// ---------------- fp32 -> bf16 convert (4 elem / thread) ----------------
__global__ __launch_bounds__(256) void cvt_kernel(const float* __restrict__ in,
                                                  u16* __restrict__ out, int n4){
  int i = blockIdx.x * 256 + threadIdx.x;
  if (i >= n4) return;
  float4 v = reinterpret_cast<const float4*>(in)[i];
  uint2 o;
  o.x = pk2bf(v.x, v.y);
  o.y = pk2bf(v.z, v.w);
  reinterpret_cast<uint2*>(out)[i] = o;
}

// merged 4-weight convert: 1024 blocks per weight
__global__ __launch_bounds__(256) void cvtw_kernel(const float* __restrict__ w0, const float* __restrict__ w1,
                                                   const float* __restrict__ w2, const float* __restrict__ w3,
                                                   u16* __restrict__ o0, u16* __restrict__ o1,
                                                   u16* __restrict__ o2, u16* __restrict__ o3){
  const int which = blockIdx.x >> 10;
  const float* in = (which==0) ? w0 : (which==1) ? w1 : (which==2) ? w2 : w3;
  u16* out = (which==0) ? o0 : (which==1) ? o1 : (which==2) ? o2 : o3;
  const int i = (blockIdx.x & 1023) * 256 + threadIdx.x;
  float4 v = reinterpret_cast<const float4*>(in)[i];
  uint2 o;
  o.x = pk2bf(v.x, v.y);
  o.y = pk2bf(v.z, v.w);
  reinterpret_cast<uint2*>(out)[i] = o;
}

// ---------------- RoPE cos/sin table: tab[s*32+i] = (cos, sin) ------------
__global__ __launch_bounds__(256) void trig_kernel(float2* __restrict__ tab){
  const int idx = blockIdx.x * 256 + threadIdx.x;   // 65536
  const int i = idx & 31, s = idx >> 5;
  const float ang = (float)s * __builtin_exp2f((float)i * -0.41524101186092032f);
  float sn, cs;
  __sincosf(ang, &sn, &cs);
  tab[idx] = make_float2(cs, sn);
}

// ---------------- fused QKV GEMM: grid (64, 24) ---------------------------
// by>>3 selects weight: 0->Q (rope+scale), 1->K (rope), 2->V (plain [M][N]).
__global__ __launch_bounds__(256) void gemm_qkv(const u16* __restrict__ A,
                                                const u16* __restrict__ W0,
                                                const u16* __restrict__ W1,
                                                const u16* __restrict__ W2,
                                                u16* __restrict__ Qh,
                                                u16* __restrict__ Kh,
                                                u16* __restrict__ Vb,
                                                const float2* __restrict__ tab){
  __shared__ __align__(16) u16 As[128*32];
  __shared__ __align__(16) u16 Bs[128*32];
  const int K = 1024, N = 1024;
  const int tid = threadIdx.x;
  const int lane = tid & 63, wid = tid >> 6;
  const int l16 = lane & 15, lq = lane >> 4;
  const int wsel = blockIdx.y >> 3;
  const u16* Bw = (wsel==0) ? W0 : (wsel==1) ? W1 : W2;
  const int m0 = blockIdx.x * 128, n0 = (blockIdx.y & 7) * 128;
  const int wr = (wid >> 1) * 64, wc = (wid & 1) * 64;
  const int srow = wid*32 + (lane >> 2);
  const int scol = (lane & 3) * 8;
  const u16* Ag = A  + (size_t)(m0 + srow) * K + scol;
  const u16* Bg = Bw + (size_t)(n0 + srow) * K + scol;
  u16* AsW = As + wid*32*32;
  u16* BsW = Bs + wid*32*32;
  f32x4 acc[4][4] = {};
  for (int k0 = 0; k0 < K; k0 += 32){
    __syncthreads();
    gload16(Ag + k0,            AsW);
    gload16(Ag + 16*(size_t)K + k0, AsW + 16*32);
    gload16(Bg + k0,            BsW);
    gload16(Bg + 16*(size_t)K + k0, BsW + 16*32);
    __syncthreads();
    short8 af[4], bfr[4];
#pragma unroll
    for (int i=0;i<4;i++) af[i]  = *reinterpret_cast<const short8*>(As + (wr + i*16 + l16)*32 + lq*8);
#pragma unroll
    for (int i=0;i<4;i++) bfr[i] = *reinterpret_cast<const short8*>(Bs + (wc + i*16 + l16)*32 + lq*8);
    __builtin_amdgcn_s_setprio(1);
#pragma unroll
    for (int i=0;i<4;i++)
#pragma unroll
      for (int j=0;j<4;j++) acc[i][j] = mfma16(af[i], bfr[j], acc[i][j]);
    __builtin_amdgcn_s_setprio(0);
  }
  const float QS = 0.18033688011112043f;  // 0.125 * log2(e)
#pragma unroll
  for (int i=0;i<4;i++){
#pragma unroll
    for (int j=0;j<4;j++){
#pragma unroll
      for (int r=0;r<4;r++){
        const int m = m0 + wr + i*16 + lq*4 + r;
        const int n = n0 + wc + j*16 + l16;
        float v = acc[i][j][r];
        if (wsel == 2){
          Vb[(size_t)m * N + n] = f2bf(v);
        } else {
          const int b = m >> 11, s = m & 2047;    // S_=2048
          const int h = n >> 6,  hd = n & 63;     // HD=64
          const float2 t = tab[(s << 5) + (hd >> 1)];
          const float partner = __shfl_xor(v, 1, 64);
          const float pm = (hd & 1) ? partner : -partner;
          float o = fmaf(v, t.x, pm * t.y);
          u16* dst = (wsel == 0) ? Qh : Kh;
          if (wsel == 0) o *= QS;
          dst[(((size_t)(b*H_ + h) * S_ + s) << 6) + hd] = f2bf(o);
        }
      }
    }
  }
}

// ---------------- O-proj GEMM: C f32 = A * B^T ----------------------------
__global__ __launch_bounds__(256) void gemm_o(const u16* __restrict__ A,
                                              const u16* __restrict__ Bw,
                                              float* __restrict__ C){
  __shared__ __align__(16) u16 As[128*32];
  __shared__ __align__(16) u16 Bs[128*32];
  const int K = 1024, N = 1024;
  const int tid = threadIdx.x;
  const int lane = tid & 63, wid = tid >> 6;
  const int l16 = lane & 15, lq = lane >> 4;
  const int m0 = blockIdx.x * 128, n0 = blockIdx.y * 128;
  const int wr = (wid >> 1) * 64, wc = (wid & 1) * 64;
  const int srow = wid*32 + (lane >> 2);
  const int scol = (lane & 3) * 8;
  const u16* Ag = A  + (size_t)(m0 + srow) * K + scol;
  const u16* Bg = Bw + (size_t)(n0 + srow) * K + scol;
  u16* AsW = As + wid*32*32;
  u16* BsW = Bs + wid*32*32;
  f32x4 acc[4][4] = {};
  for (int k0 = 0; k0 < K; k0 += 32){
    __syncthreads();
    gload16(Ag + k0,            AsW);
    gload16(Ag + 16*(size_t)K + k0, AsW + 16*32);
    gload16(Bg + k0,            BsW);
    gload16(Bg + 16*(size_t)K + k0, BsW + 16*32);
    __syncthreads();
    short8 af[4], bfr[4];
#pragma unroll
    for (int i=0;i<4;i++) af[i]  = *reinterpret_cast<const short8*>(As + (wr + i*16 + l16)*32 + lq*8);
#pragma unroll
    for (int i=0;i<4;i++) bfr[i] = *reinterpret_cast<const short8*>(Bs + (wc + i*16 + l16)*32 + lq*8);
    __builtin_amdgcn_s_setprio(1);
#pragma unroll
    for (int i=0;i<4;i++)
#pragma unroll
      for (int j=0;j<4;j++) acc[i][j] = mfma16(af[i], bfr[j], acc[i][j]);
    __builtin_amdgcn_s_setprio(0);
  }
#pragma unroll
  for (int i=0;i<4;i++)
#pragma unroll
    for (int j=0;j<4;j++)
#pragma unroll
      for (int r=0;r<4;r++){
        const int m = m0 + wr + i*16 + lq*4 + r;
        const int n = n0 + wc + j*16 + l16;
        C[(size_t)m * N + n] = acc[i][j][r];
      }
}

// ---------------- V [B,S,D] -> V^T [B*H][HD=64][S] ----------------
__global__ __launch_bounds__(256) void vt_kernel(const u16* __restrict__ V, u16* __restrict__ Vt){
  __shared__ __align__(16) u16 t[64*80];
  const int bh = blockIdx.y, b = bh >> 4, h = bh & 15;
  const int s0 = blockIdx.x * 64;
  const int tid = threadIdx.x;
  const int r = tid >> 3, seg = tid & 7;
#pragma unroll
  for (int p=0;p<2;p++){
    const int row = r + p*32;   // s offset
    ushort8 v = *reinterpret_cast<const ushort8*>(V + (size_t)(b*S_ + s0 + row)*D_ + h*64 + seg*8);
    *reinterpret_cast<ushort8*>(t + row*80 + seg*8) = v;
  }
  __syncthreads();
#pragma unroll
  for (int p=0;p<2;p++){
    const int hd = r + p*32;
    ushort8 o;
#pragma unroll
    for (int j=0;j<8;j++) o[j] = t[(seg*8+j)*80 + hd];
    *reinterpret_cast<ushort8*>(Vt + ((size_t)bh*64 + hd)*S_ + s0 + seg*8) = o;
  }
}

// ---------------- causal flash attention: 32x32 MFMA, in-register P -------
// Q,K: [BH][S][64] (Q pre-scaled into exp2 domain), Vt: [BH][64][S], O: [B,S,D]
// 4 waves x 32 q-cols = QBLK 128; pairs {15-px, px} -> 36 KV-tiles/block;
// grid 64x8 = 2 blocks/CU. KV dbuf via gload_lds + XOR swizzle (32 KB LDS).
// QK/PV use mfma 32x32x16 (half the LDS bytes per element of 16x16).
// Softmax S^T: lane q = lane&31, 32 k-vals in regs; m reduce = 1 shfl_xor(32).
// P -> PV B-fragments fully in-register: cvt_pk pairs + v_permlane32_swap.
// l via ones-MFMA (lacc[0]).
__global__ __launch_bounds__(256) void attn_kernel(const u16* __restrict__ Q,
                                                   const u16* __restrict__ Kg,
                                                   const u16* __restrict__ Vt,
                                                   u16* __restrict__ O){
  __shared__ __align__(16) u16 KV[2][2][4096];   // [buf][K|V][row*64+col] 32 KB
  const int bh = blockIdx.x;                     // fastest -> XCD = bh%8
  const int px = blockIdx.y;                     // pair index 0..7
  const int tid = threadIdx.x, wid = tid >> 6, lane = tid & 63;
  const int l32 = lane & 31, hh = lane >> 5;
  const u16* Qb = Q  + (size_t)bh * S_ * 64;
  const u16* Kb = Kg + (size_t)bh * S_ * 64;
  const u16* Vb = Vt + (size_t)bh * 64 * S_;
  const int b = bh >> 4, head = bh & 15;
  const short8 ones8 = {0x3F80,0x3F80,0x3F80,0x3F80,0x3F80,0x3F80,0x3F80,0x3F80};
  const f32x16 Z16 = {};

  // staging: thread covers 16B at rows (tid>>3) and (tid>>3)+32 of 64x64 tile
  const int LoffA = tid*8;                    // u16 offset, rows 0..31
  const int rowA  = tid >> 3;
  const int swzA  = LoffA ^ ((rowA & 7) << 3);
  const int swzB  = swzA + 2048;              // rows 32..63 (same row&7)
  const int vcolA = swzA & 63, vcolB = vcolA; // col bits identical
  const int rsw   = (l32 & 7) << 3;           // read-side swizzle

#pragma unroll 1
  for (int half = 0; half < 2; ++half){
    const int qt = half ? px : (15 - px);
    const int q0 = qt * 128;
    const int qw0 = q0 + wid*32;              // wave q base
    const int qg = qw0 + l32;                 // this lane's q row
    short8 qf[4];
#pragma unroll
    for (int j=0;j<4;j++)
      qf[j] = *reinterpret_cast<const short8*>(Qb + (size_t)qg*64 + j*16 + hh*8);
    float m_run = -1e30f;
    f32x16 oacc0 = Z16, oacc1 = Z16, lacc = Z16;

    const int nt = 2*qt + 2;
    // prologue: stage tile 0 into buf 0 (K rows 0..63, V rows 0..63)
    gload16(Kb + swzA,                         &KV[0][0][wid*512]);
    gload16(Kb + swzB,                         &KV[0][0][wid*512 + 2048]);
    gload16(Vb + (size_t)rowA*S_ + vcolA,      &KV[0][1][wid*512]);
    gload16(Vb + (size_t)(rowA+32)*S_ + vcolB, &KV[0][1][wid*512 + 2048]);
    __syncthreads();

#pragma unroll 1
    for (int kt = 0; kt < nt; ++kt){
      const int cur = kt & 1;
      if (kt + 1 < nt){
        const int kn = (kt + 1) * 64;
        gload16(Kb + (size_t)kn*64 + swzA,            &KV[cur^1][0][wid*512]);
        gload16(Kb + (size_t)kn*64 + swzB,            &KV[cur^1][0][wid*512 + 2048]);
        gload16(Vb + (size_t)rowA*S_ + kn + vcolA,    &KV[cur^1][1][wid*512]);
        gload16(Vb + (size_t)(rowA+32)*S_ + kn + vcolB,&KV[cur^1][1][wid*512 + 2048]);
      }
      const int k0 = kt * 64;
      if (k0 <= qw0 + 31){   // wave has at least one unmasked q
        const u16* Kc = &KV[cur][0][0];
        const u16* Vc = &KV[cur][1][0];
        // QK^T: sc[kb] = K-block(32k) x Q(32q); lane: q=l32, k=(r&3)+8(r>>2)+4hh
        f32x16 sc0 = Z16, sc1 = Z16;
        __builtin_amdgcn_s_setprio(1);
#pragma unroll
        for (int j=0;j<4;j++){
          short8 kf0 = *reinterpret_cast<const short8*>(Kc + l32*64        + ((j*16 + hh*8) ^ rsw));
          short8 kf1 = *reinterpret_cast<const short8*>(Kc + (32+l32)*64   + ((j*16 + hh*8) ^ rsw));
          sc0 = mfma32(kf0, qf[j], sc0);
          sc1 = mfma32(kf1, qf[j], sc1);
        }
        __builtin_amdgcn_s_setprio(0);
        if (k0 + 63 > qw0){   // element mask in diagonal region
#pragma unroll
          for (int r=0;r<16;r++){
            const int kk = k0 + (r&3) + 8*(r>>2) + 4*hh;
            if (kk > qg)      sc0[r] = -1e30f;
            if (kk + 32 > qg) sc1[r] = -1e30f;
          }
        }
        // per-lane max over 32 values
        float mx0 = fmaxf(sc0[0], sc0[1]);
#pragma unroll
        for (int r=2;r<16;r++) mx0 = fmaxf(mx0, sc0[r]);
        float mx1 = fmaxf(sc1[0], sc1[1]);
#pragma unroll
        for (int r=2;r<16;r++) mx1 = fmaxf(mx1, sc1[r]);
        float lmx = fmaxf(mx0, mx1);
        if (__any(lmx > m_run + 8.f)){
          float mx = fmaxf(lmx, __shfl_xor(lmx, 32, 64));
          mx = fmaxf(mx, m_run);
          const float alpha = __builtin_exp2f(m_run - mx);
          m_run = mx;
          lacc[0] *= alpha;
#pragma unroll
          for (int r=0;r<16;r++){ oacc0[r] *= alpha; oacc1[r] *= alpha; }
        }
        // P = exp2(S - m) in place
#pragma unroll
        for (int r=0;r<16;r++){
          sc0[r] = __builtin_exp2f(sc0[r] - m_run);
          sc1[r] = __builtin_exp2f(sc1[r] - m_run);
        }
        // per 16-k block: pack to bf16, permlane-swap into PV B-frags, MFMA
        __builtin_amdgcn_s_setprio(1);
#pragma unroll
        for (int blk=0; blk<4; ++blk){
          const f32x16 S = (blk < 2) ? sc0 : sc1;
          const int r0 = (blk & 1) * 8;
          u32 a0 = pk2bf(S[r0+0], S[r0+1]);
          u32 a1 = pk2bf(S[r0+2], S[r0+3]);
          u32 b0 = pk2bf(S[r0+4], S[r0+5]);
          u32 b1 = pk2bf(S[r0+6], S[r0+7]);
          plswap(a0, b0);
          plswap(a1, b1);
          u32x4 t4; t4[0]=a0; t4[1]=a1; t4[2]=b0; t4[3]=b1;
          const short8 pf = __builtin_bit_cast(short8, t4);
          lacc = mfma32(ones8, pf, lacc);          // row-sum of P
          short8 vf0 = *reinterpret_cast<const short8*>(Vc + l32*64      + ((blk*16 + hh*8) ^ rsw));
          short8 vf1 = *reinterpret_cast<const short8*>(Vc + (32+l32)*64 + ((blk*16 + hh*8) ^ rsw));
          oacc0 = mfma32(vf0, pf, oacc0);
          oacc1 = mfma32(vf1, pf, oacc1);
        }
        __builtin_amdgcn_s_setprio(0);
      }
      __syncthreads();   // drains vmcnt (prefetch landed) + all waves done with cur
    }
    // epilogue: lacc[0] = sum_k P for q=qg; O[q][d], d = 32*dt + 8*q4 + 4*hh + j
    const float linv = __builtin_amdgcn_rcpf(lacc[0]);
    u16* Orow = O + (size_t)(b*S_ + qg)*D_ + head*64;
#pragma unroll
    for (int q4=0;q4<4;q4++){
      uint2 o0, o1;
      o0.x = pk2bf(oacc0[q4*4+0]*linv, oacc0[q4*4+1]*linv);
      o0.y = pk2bf(oacc0[q4*4+2]*linv, oacc0[q4*4+3]*linv);
      o1.x = pk2bf(oacc1[q4*4+0]*linv, oacc1[q4*4+1]*linv);
      o1.y = pk2bf(oacc1[q4*4+2]*linv, oacc1[q4*4+3]*linv);
      *reinterpret_cast<uint2*>(Orow + q4*8 + hh*4)      = o0;
      *reinterpret_cast<uint2*>(Orow + 32 + q4*8 + hh*4) = o1;
    }
  }
}

extern "C" void kernel_launch(void* const* d_in, const int* in_sizes, int n_in,
                              void* d_out, int out_size, void* d_ws, size_t ws_size,
                              hipStream_t stream){
  const float* x  = (const float*)d_in[0];
  const float* Wq = (const float*)d_in[1];
  const float* Wk = (const float*)d_in[2];
  const float* Wv = (const float*)d_in[3];
  const float* Wo = (const float*)d_in[4];
  char* ws = (char*)d_ws;
  u16* xb  = (u16*)(ws);                               // 16 MiB  x bf16
  u16* Wqb = (u16*)(ws + (16u<<20));                   // 2 MiB
  u16* Wkb = (u16*)(ws + (16u<<20) + (2u<<20));
  u16* Wvb = (u16*)(ws + (16u<<20) + (4u<<20));
  u16* Wob = (u16*)(ws + (16u<<20) + (6u<<20));
  u16* Qh  = (u16*)(ws + (24u<<20));                   // 16 MiB [BH][S][64]
  u16* Kh  = (u16*)(ws + (40u<<20));                   // 16 MiB
  u16* Vb  = (u16*)(ws + (56u<<20));                   // 16 MiB [B,S,D]
  u16* Vt  = (u16*)(ws + (72u<<20));                   // 16 MiB [BH][64][S]
  float2* tab = (float2*)(ws + (88u<<20));             // 512 KiB rope table
  u16* Ob  = Vb;                                       // alias: V dead after vt_kernel

  cvt_kernel<<<8192, 256, 0, stream>>>(x, xb, 2097152);
  cvtw_kernel<<<4096, 256, 0, stream>>>(Wq, Wk, Wv, Wo, Wqb, Wkb, Wvb, Wob);
  trig_kernel<<<256, 256, 0, stream>>>(tab);

  gemm_qkv<<<dim3(64,24), 256, 0, stream>>>(xb, Wqb, Wkb, Wvb, Qh, Kh, Vb, tab);

  vt_kernel<<<dim3(32,64), 256, 0, stream>>>(Vb, Vt);
  attn_kernel<<<dim3(64,8), 256, 0, stream>>>(Qh, Kh, Vt, Ob);

  gemm_o<<<dim3(64,8), 256, 0, stream>>>(Ob, Wob, (float*)d_out);
}